// Round 10
// baseline (412.849 us; speedup 1.0000x reference)
//
#include <hip/hip_runtime.h>

// ChamferLossSelf: B=4, N=4096, D=3, fp32 in/out. out = loss1 + loss2 + ALPHA*ordering.
constexpr int BATCH = 4;
constexpr int NPTS  = 4096;
constexpr int QC    = 1024;  // queries per block
constexpr int TC    = 512;   // targets per block (staged in LDS)
constexpr int NTHR  = 256;
constexpr int QPT   = QC / NTHR;  // 4 queries per thread

// ws: uint nnmin[4][BATCH][NPTS] (float bits; memset 0x7F = 3.4e38 start; atomicMin valid, d>=0)
// slot0: per-gts NN among preds -> loss_2   slot1: per-pred NN among gts -> loss_1
// slot2: gts self-NN (diag excl) -> mins1   slot3: preds self-NN (diag excl) -> mins2

__global__ __launch_bounds__(NTHR) void nn_pass(const float* __restrict__ gts,
                                                const float* __restrict__ preds,
                                                unsigned int* __restrict__ nnmin) {
    const int pass  = blockIdx.z & 3;
    const int b     = blockIdx.z >> 2;
    const int qbase = blockIdx.y * QC;
    const int tbase = blockIdx.x * TC;
    const bool selfp = (pass >= 2);
    const float* __restrict__ A = (pass == 0 || pass == 2) ? gts : preds;
    const float* __restrict__ T = (pass == 1 || pass == 2) ? gts : preds;

    __shared__ float4 tp[TC];  // 8 KB
    for (int k = threadIdx.x; k < TC; k += NTHR) {
        const float* p = T + ((size_t)b * NPTS + tbase + k) * 3;
        tp[k] = make_float4(p[0], p[1], p[2], 0.f);
    }
    __syncthreads();

    float qx[QPT], qy[QPT], qz[QPT], mn[QPT];
    int qidx[QPT];
#pragma unroll
    for (int q = 0; q < QPT; ++q) {
        const int qi = qbase + threadIdx.x + q * NTHR;
        qidx[q] = qi;
        const float* p = A + ((size_t)b * NPTS + qi) * 3;
        qx[q] = p[0]; qy[q] = p[1]; qz[q] = p[2];
        mn[q] = 1e30f;
    }

    if (selfp) {
#pragma unroll 4
        for (int j = 0; j < TC; ++j) {
            const float4 t = tp[j];
            const int tj = tbase + j;
#pragma unroll
            for (int q = 0; q < QPT; ++q) {
                const float dx = qx[q] - t.x, dy = qy[q] - t.y, dz = qz[q] - t.z;
                float d = dx * dx;
                d = fmaf(dy, dy, d);
                d = fmaf(dz, dz, d);
                d = (tj == qidx[q]) ? 1e30f : d;  // diag excluded (== DIAG_FILL semantics)
                mn[q] = fminf(mn[q], d);
            }
        }
    } else {
#pragma unroll 4
        for (int j = 0; j < TC; ++j) {
            const float4 t = tp[j];
#pragma unroll
            for (int q = 0; q < QPT; ++q) {
                const float dx = qx[q] - t.x, dy = qy[q] - t.y, dz = qz[q] - t.z;
                float d = dx * dx;
                d = fmaf(dy, dy, d);
                d = fmaf(dz, dz, d);
                mn[q] = fminf(mn[q], d);
            }
        }
    }

    unsigned int* dst = nnmin + ((size_t)pass * BATCH + b) * NPTS;
#pragma unroll
    for (int q = 0; q < QPT; ++q)
        atomicMin(&dst[qidx[q]], __float_as_uint(mn[q]));
}

// 4 blocks x 256 threads. Waves 0/1: wave-register bitonic sort of slot2/slot3
// (64 keys/lane, i = lane*64+e; j<64 in-register, j>=64 shfl_xor; zero barriers).
// Waves 2/3: cross-NN sums meanwhile. Then ordering diff-sum + block reduce.
__global__ __launch_bounds__(256) void nn_final(const unsigned int* __restrict__ nnmin,
                                                float* __restrict__ out) {
    const int b    = blockIdx.x;
    const int tid  = threadIdx.x;
    const int wave = tid >> 6;
    const int lane = tid & 63;
    __shared__ float sA[NPTS];  // 16 KB (transposed layout t = e*64+lane)
    __shared__ float sB[NPTS];  // 16 KB (same bijection -> diff-sum unaffected)
    __shared__ float red[256];

    float part = 0.f;

    if (wave < 2) {
        const unsigned int* src = nnmin + ((size_t)(2 + wave) * BATCH + b) * NPTS;
        float v[64];
#pragma unroll
        for (int e4 = 0; e4 < 16; ++e4) {
            const uint4 u = reinterpret_cast<const uint4*>(src)[lane * 16 + e4];
            v[e4 * 4 + 0] = __uint_as_float(u.x);
            v[e4 * 4 + 1] = __uint_as_float(u.y);
            v[e4 * 4 + 2] = __uint_as_float(u.z);
            v[e4 * 4 + 3] = __uint_as_float(u.w);
        }

        // bitonic sort of 4096 keys within one wave
#pragma unroll
        for (int lk = 1; lk <= 12; ++lk) {
            const int k = 1 << lk;
#pragma unroll
            for (int lj = lk - 1; lj >= 0; --lj) {
                const int j = 1 << lj;
                if (j >= 64) {  // cross-lane: partner lane = lane ^ (j>>6), same e
                    const int lm = j >> 6;
                    const bool asc = ((lane & (k >> 6)) == 0);   // k >= 128 here
                    const bool keepmin = (((lane & lm) == 0) == asc);
#pragma unroll
                    for (int e = 0; e < 64; ++e) {
                        const float pv = __shfl_xor(v[e], lm, 64);
                        v[e] = keepmin ? fminf(v[e], pv) : fmaxf(v[e], pv);
                    }
                } else if (k >= 64) {  // in-register pairs, lane-uniform direction
                    const bool asc = ((lane & (k >> 6)) == 0);
#pragma unroll
                    for (int e = 0; e < 64; ++e) {
                        if ((e & j) == 0) {
                            const int p = e | j;
                            const float a = v[e], c = v[p];
                            v[e] = asc ? fminf(a, c) : fmaxf(a, c);
                            v[p] = asc ? fmaxf(a, c) : fminf(a, c);
                        }
                    }
                } else {  // in-register pairs, compile-time direction
#pragma unroll
                    for (int e = 0; e < 64; ++e) {
                        if ((e & j) == 0) {
                            const int p = e | j;
                            const bool asc = ((e & k) == 0);
                            const float a = v[e], c = v[p];
                            v[e] = asc ? fminf(a, c) : fmaxf(a, c);
                            v[p] = asc ? fmaxf(a, c) : fminf(a, c);
                        }
                    }
                }
            }
        }

        // transposed store t = e*64 + lane: lanes consecutive -> conflict-free
        float* dst = (wave == 0) ? sA : sB;
#pragma unroll
        for (int e = 0; e < 64; ++e) dst[e * 64 + lane] = v[e];
    } else {
        // cross-NN sums: slots 0 and 1, 128 threads x 32 floats each per slot
        const int local = tid - 128;  // 0..127
        const float* m0 = (const float*)(nnmin + ((size_t)0 * BATCH + b) * NPTS);
        const float* m1 = (const float*)(nnmin + ((size_t)1 * BATCH + b) * NPTS);
#pragma unroll
        for (int i = 0; i < 8; ++i) {
            const float4 u0 = reinterpret_cast<const float4*>(m0)[local + 128 * i];
            const float4 u1 = reinterpret_cast<const float4*>(m1)[local + 128 * i];
            part += u0.x + u0.y + u0.z + u0.w + u1.x + u1.y + u1.z + u1.w;
        }
    }
    __syncthreads();

    // ordering term: same bijective layout in sA/sB -> sum of squared diffs is exact
#pragma unroll
    for (int e = 0; e < 16; ++e) {
        const int t = tid + 256 * e;  // stride-1 across lanes: conflict-free
        const float d = sA[t] - sB[t];
        part = fmaf(d, d, part);  // ALPHA = 1
    }

    red[tid] = part;
    __syncthreads();
    for (int s = 128; s > 0; s >>= 1) {
        if (tid < s) red[tid] += red[tid + s];
        __syncthreads();
    }
    if (tid == 0) out[b] = red[0];
}

extern "C" void kernel_launch(void* const* d_in, const int* in_sizes, int n_in,
                              void* d_out, int out_size, void* d_ws, size_t ws_size,
                              hipStream_t stream) {
    const float* gts   = (const float*)d_in[0];
    const float* preds = (const float*)d_in[1];
    float* out = (float*)d_out;
    unsigned int* nnmin = (unsigned int*)d_ws;  // 4*BATCH*NPTS uints = 256 KB

    // init all slots to 0x7F7F7F7F (~3.4e38 as float) for atomicMin
    hipMemsetAsync(d_ws, 0x7F, (size_t)4 * BATCH * NPTS * sizeof(unsigned int), stream);
    dim3 grid(NPTS / TC, NPTS / QC, BATCH * 4);  // (8, 4, 16) = 512 blocks
    nn_pass<<<grid, NTHR, 0, stream>>>(gts, preds, nnmin);
    nn_final<<<BATCH, 256, 0, stream>>>(nnmin, out);
}

// Round 12
// 122.970 us; speedup vs baseline: 3.3573x; 3.3573x over previous
//
#include <hip/hip_runtime.h>

// ChamferLossSelf: B=4, N=4096, D=3, fp32 in/out. out = loss1 + loss2 + ALPHA*ordering.
constexpr int BATCH = 4;
constexpr int NPTS  = 4096;
constexpr int QC    = 1024;  // queries per block
constexpr int TC    = 512;   // targets per block (staged in LDS)
constexpr int NTHR  = 256;
constexpr int QPT   = QC / NTHR;  // 4 queries per thread
constexpr int PADN  = NPTS + (NPTS >> 4);  // 4352 (pad 1 float per 16 -> 17t+e layout)

// ws: uint nnmin[4][BATCH][NPTS] (float bits; memset 0x7F = 3.4e38 start; atomicMin valid, d>=0)
// slot0: per-gts NN among preds -> loss_2   slot1: per-pred NN among gts -> loss_1
// slot2: gts self-NN (diag excl) -> mins1   slot3: preds self-NN (diag excl) -> mins2

__global__ __launch_bounds__(NTHR) void nn_pass(const float* __restrict__ gts,
                                                const float* __restrict__ preds,
                                                unsigned int* __restrict__ nnmin) {
    const int pass  = blockIdx.z & 3;
    const int b     = blockIdx.z >> 2;
    const int qbase = blockIdx.y * QC;
    const int tbase = blockIdx.x * TC;
    const bool selfp = (pass >= 2);
    const float* __restrict__ A = (pass == 0 || pass == 2) ? gts : preds;
    const float* __restrict__ T = (pass == 1 || pass == 2) ? gts : preds;

    __shared__ float4 tp[TC];  // 8 KB
    for (int k = threadIdx.x; k < TC; k += NTHR) {
        const float* p = T + ((size_t)b * NPTS + tbase + k) * 3;
        tp[k] = make_float4(p[0], p[1], p[2], 0.f);
    }
    __syncthreads();

    float qx[QPT], qy[QPT], qz[QPT], mn[QPT];
    int qidx[QPT];
#pragma unroll
    for (int q = 0; q < QPT; ++q) {
        const int qi = qbase + threadIdx.x + q * NTHR;
        qidx[q] = qi;
        const float* p = A + ((size_t)b * NPTS + qi) * 3;
        qx[q] = p[0]; qy[q] = p[1]; qz[q] = p[2];
        mn[q] = 1e30f;
    }

    if (selfp) {
#pragma unroll 4
        for (int j = 0; j < TC; ++j) {
            const float4 t = tp[j];
            const int tj = tbase + j;
#pragma unroll
            for (int q = 0; q < QPT; ++q) {
                const float dx = qx[q] - t.x, dy = qy[q] - t.y, dz = qz[q] - t.z;
                float d = dx * dx;
                d = fmaf(dy, dy, d);
                d = fmaf(dz, dz, d);
                d = (tj == qidx[q]) ? 1e30f : d;  // diag excluded (== DIAG_FILL semantics)
                mn[q] = fminf(mn[q], d);
            }
        }
    } else {
#pragma unroll 4
        for (int j = 0; j < TC; ++j) {
            const float4 t = tp[j];
#pragma unroll
            for (int q = 0; q < QPT; ++q) {
                const float dx = qx[q] - t.x, dy = qy[q] - t.y, dz = qz[q] - t.z;
                float d = dx * dx;
                d = fmaf(dy, dy, d);
                d = fmaf(dz, dz, d);
                mn[q] = fminf(mn[q], d);
            }
        }
    }

    unsigned int* dst = nnmin + ((size_t)pass * BATCH + b) * NPTS;
#pragma unroll
    for (int q = 0; q < QPT; ++q)
        atomicMin(&dst[qidx[q]], __float_as_uint(mn[q]));
}

// ---- bitonic sort of 4096 floats by a 256-thread group, 16 keys/lane, i = 16t+e ----
// J<16: in-register (static idx). 16<=J<=512: shfl_xor. J in {1024,2048}: padded-LDS
// exchange (addr 17t+e; 17 odd -> bijective mod 32 -> conflict-free). All steps are
// template instantiations -> J,K constexpr -> guaranteed register residency (rule #20).

template<int K, int J>
__device__ __forceinline__ void bstep(float (&v)[16], const int t, float* __restrict__ sbuf) {
    if constexpr (J >= 1024) {
        const bool asc = ((t & (K >> 4)) == 0);
        const bool keepmin = (((t & (J >> 4)) == 0) == asc);
        const int tp = t ^ (J >> 4);
#pragma unroll
        for (int e = 0; e < 16; ++e) sbuf[17 * t + e] = v[e];
        __syncthreads();
#pragma unroll
        for (int e = 0; e < 16; ++e) {
            const float pv = sbuf[17 * tp + e];
            v[e] = keepmin ? fminf(v[e], pv) : fmaxf(v[e], pv);
        }
        __syncthreads();  // WAR: sbuf reused by later exchanges / final store
    } else if constexpr (J >= 16) {
        constexpr int lm = J >> 4;  // < 64: stays within wave
        const bool asc = ((t & (K >> 4)) == 0);
        const bool keepmin = (((t & lm) == 0) == asc);
#pragma unroll
        for (int e = 0; e < 16; ++e) {
            const float pv = __shfl_xor(v[e], lm, 64);
            v[e] = keepmin ? fminf(v[e], pv) : fmaxf(v[e], pv);
        }
    } else {
#pragma unroll
        for (int e = 0; e < 16; ++e) {
            if ((e & J) == 0) {  // constexpr-foldable per unrolled e
                const int p = e | J;
                bool asc;
                if constexpr (K >= 16) asc = ((t & (K >> 4)) == 0);
                else                   asc = ((e & K) == 0);
                const float a = v[e], c = v[p];
                v[e] = asc ? fminf(a, c) : fmaxf(a, c);
                v[p] = asc ? fmaxf(a, c) : fminf(a, c);
            }
        }
    }
}

template<int K, int J>
__device__ __forceinline__ void bseq(float (&v)[16], const int t, float* __restrict__ sbuf) {
    bstep<K, J>(v, t, sbuf);
    if constexpr (J > 1) bseq<K, (J >> 1)>(v, t, sbuf);
}

template<int K>
__device__ __forceinline__ void bsortk(float (&v)[16], const int t, float* __restrict__ sbuf) {
    bseq<K, (K >> 1)>(v, t, sbuf);
    if constexpr (K < NPTS) bsortk<(K << 1)>(v, t, sbuf);
}

// 4 blocks x 512 threads. Group g = tid>>8 sorts slot(2+g); then all threads do
// cross-NN sums + ordering diff-sum + block reduce.
__global__ __launch_bounds__(512) void nn_final(const unsigned int* __restrict__ nnmin,
                                                float* __restrict__ out) {
    const int b   = blockIdx.x;
    const int tid = threadIdx.x;
    const int g   = tid >> 8;    // 0 or 1
    const int t   = tid & 255;
    __shared__ float s[2][PADN];  // 34 KB
    __shared__ float red[512];
    float* sbuf = s[g];

    const unsigned int* src = nnmin + ((size_t)(2 + g) * BATCH + b) * NPTS;
    float v[16];
#pragma unroll
    for (int q = 0; q < 4; ++q) {
        const uint4 u = reinterpret_cast<const uint4*>(src)[t * 4 + q];
        v[q * 4 + 0] = __uint_as_float(u.x);
        v[q * 4 + 1] = __uint_as_float(u.y);
        v[q * 4 + 2] = __uint_as_float(u.z);
        v[q * 4 + 3] = __uint_as_float(u.w);
    }

    bsortk<2>(v, t, sbuf);  // identical instruction stream in both groups -> uniform barriers

    // final store (padded, conflict-free)
#pragma unroll
    for (int e = 0; e < 16; ++e) sbuf[17 * t + e] = v[e];
    __syncthreads();

    float part = 0.f;
    const float* m0 = (const float*)(nnmin + ((size_t)0 * BATCH + b) * NPTS);
    const float* m1 = (const float*)(nnmin + ((size_t)1 * BATCH + b) * NPTS);
#pragma unroll
    for (int q = 0; q < 2; ++q) {
        const float4 u0 = reinterpret_cast<const float4*>(m0)[tid + 512 * q];
        const float4 u1 = reinterpret_cast<const float4*>(m1)[tid + 512 * q];
        part += u0.x + u0.y + u0.z + u0.w + u1.x + u1.y + u1.z + u1.w;
    }
#pragma unroll
    for (int e = 0; e < 8; ++e) {
        const int i  = tid + 512 * e;
        const int pi = i + (i >> 4);
        const float d = s[0][pi] - s[1][pi];
        part = fmaf(d, d, part);  // ALPHA = 1
    }

    red[tid] = part;
    __syncthreads();
    for (int sh = 256; sh > 0; sh >>= 1) {
        if (tid < sh) red[tid] += red[tid + sh];
        __syncthreads();
    }
    if (tid == 0) out[b] = red[0];
}

extern "C" void kernel_launch(void* const* d_in, const int* in_sizes, int n_in,
                              void* d_out, int out_size, void* d_ws, size_t ws_size,
                              hipStream_t stream) {
    const float* gts   = (const float*)d_in[0];
    const float* preds = (const float*)d_in[1];
    float* out = (float*)d_out;
    unsigned int* nnmin = (unsigned int*)d_ws;  // 4*BATCH*NPTS uints = 256 KB

    // init all slots to 0x7F7F7F7F (~3.4e38 as float) for atomicMin
    hipMemsetAsync(d_ws, 0x7F, (size_t)4 * BATCH * NPTS * sizeof(unsigned int), stream);
    dim3 grid(NPTS / TC, NPTS / QC, BATCH * 4);  // (8, 4, 16) = 512 blocks
    nn_pass<<<grid, NTHR, 0, stream>>>(gts, preds, nnmin);
    nn_final<<<BATCH, 512, 0, stream>>>(nnmin, out);
}